// Round 8
// baseline (57.697 us; speedup 1.0000x reference)
//
#include <hip/hip_runtime.h>

#define NB 1024          // B
#define LSZ 128          // L
#define PTS_FLOATS (NB * 3 * LSZ * LSZ)     // 50,331,648
#define PTS4 (PTS_FLOATS / 4)               // 12,582,912 float4
#define TOT4 (PTS4 + NB * LSZ * LSZ / 4)    // 16,777,216 float4 = out_size/4 exactly
#define NBLK_PTS (NB * 3)                   // 3072 pts blocks (one per (b,i) slice)
#define NBLK_ALL (NBLK_PTS + NB)            // + 1024 phase blocks

// Native vector type: __builtin_nontemporal_store requires a scalar or
// NATIVE vector pointee (HIP's float4 class is rejected — round-7 compile).
typedef float f32x4 __attribute__((ext_vector_type(4)));

// Split grid. pts blocks use the EXACT per-element statement structure of the
// round-4 PASSING kernel (single-use mul chain -> fma contraction -> same
// last-ulp rounding at mod-2pi wrap boundaries; round-5 proved hoisting the
// a*x product flips a wrap). This round: nontemporal 16B stores via f32x4.
__global__ __launch_bounds__(256) void pose_split_kernel(
    const float* __restrict__ rotvec,
    const float* __restrict__ offs,
    const int* __restrict__ index,
    float* __restrict__ out,
    int out_n4) {
    const float PI_F   = (float)3.14159265358979323846;   // fl32(pi)
    const float TWO_PI = (float)6.28318530717958647692;   // fl32(2*pi)
    const float CPS    = (float)0.04908738521234052;      // fl32(2*pi/128)

    if (out_n4 < TOT4) return;   // defensive: harness sizing contract

    int t   = blockIdx.x;
    int tid = threadIdx.x;
    f32x4* out4 = reinterpret_cast<f32x4*>(out);

    if (t < NBLK_PTS) {
        int b = (int)((unsigned)t / 3u);
        int i = t - b * 3;
        int id = index[b];
        float rx = rotvec[id * 3 + 0];
        float ry = rotvec[id * 3 + 1];
        float rz = rotvec[id * 3 + 2];
        // theta = ||r||, sum order ((x^2+y^2)+z^2), all f32
        float theta = sqrtf(__fadd_rn(__fadd_rn(__fmul_rn(rx, rx), __fmul_rn(ry, ry)),
                                      __fmul_rn(rz, rz)));
        float denom = __fadd_rn(theta, 1e-6f);
        float kx = __fdiv_rn(rx, denom);
        float ky = __fdiv_rn(ry, denom);
        float kz = __fdiv_rn(rz, denom);
        float s  = sinf(theta);
        float c1 = __fsub_rn(1.0f, cosf(theta));
        float kx2 = __fmul_rn(kx, kx), ky2 = __fmul_rn(ky, ky), kz2 = __fmul_rn(kz, kz);
        float kxky = __fmul_rn(kx, ky), kxkz = __fmul_rn(kx, kz), kykz = __fmul_rn(ky, kz);
        float K2_00 = __fadd_rn(-kz2, -ky2);
        float K2_10 = kxky;
        float K2_20 = kxkz;
        float K2_01 = kxky;
        float K2_11 = __fadd_rn(-kz2, -kx2);
        float K2_21 = kykz;
        float R00 = __fadd_rn(1.0f, __fmul_rn(c1, K2_00));
        float R10 = __fadd_rn(__fmul_rn(s, kz),  __fmul_rn(c1, K2_10));
        float R20 = __fadd_rn(__fmul_rn(s, -ky), __fmul_rn(c1, K2_20));
        float R01 = __fadd_rn(__fmul_rn(s, -kz), __fmul_rn(c1, K2_01));
        float R11 = __fadd_rn(1.0f, __fmul_rn(c1, K2_11));
        float R21 = __fadd_rn(__fmul_rn(s, kx),  __fmul_rn(c1, K2_21));
        // Row reversal: slice i uses R row (2-i), cols 0 (x) and 1 (y)
        float a = (i == 0) ? R20 : (i == 1) ? R10 : R00;
        float c = (i == 0) ? R21 : (i == 1) ? R11 : R01;

        int base4 = t * 4096;    // == (b*3+i)*4096
        // EXACT round-4 inner loop body (statement-for-statement).
        for (int k4 = tid; k4 < 4096; k4 += 256) {
            int k0  = k4 << 2;
            int row = k0 >> 7;                       // 4 consecutive never cross a row
            float y  = __fmul_rn(PI_F, (float)(row - 64) * 0.015625f);
            float cy = __fmul_rn(c, y);
            f32x4 o;
#pragma unroll
            for (int q = 0; q < 4; ++q) {
                int col = ((k0 + q) & 127) - 64;
                float x = __fmul_rn(PI_F, (float)col * 0.015625f);
                float v = __fadd_rn(__fmul_rn(a, x), cy);  // single-use mul chain
                float w = __fadd_rn(v, PI_F);
                // exact mod(w, 2pi) for w in (-2pi, 2*2pi)
                float r = (w >= TWO_PI) ? __fsub_rn(w, TWO_PI) : w;
                r = (r < 0.0f) ? __fadd_rn(r, TWO_PI) : r;
                o[q] = __fsub_rn(r, PI_F);
            }
            __builtin_nontemporal_store(o, &out4[base4 + k4]);
        }
    } else {
        int b  = t - NBLK_PTS;
        int id = index[b];
        float off0 = -offs[id * 2 + 0];
        float off1 = -offs[id * 2 + 1];

        // Hoist is SAFE here: cos is continuous, ~1e-5 rad arg perturbation
        // cannot cross any cliff (threshold 0.0628).
        int j0 = (tid & 31) << 2;
        float bx[4];
#pragma unroll
        for (int q = 0; q < 4; ++q) {
            float g2j = __fmul_rn(CPS, (float)(j0 + q - 64));
            bx[q] = __fmul_rn(g2j, off0);
        }

        int baseg = PTS4 + b * 4096;
        for (int g = tid; g < 4096; g += 256) {
            int i = g >> 5;            // row 0..127
            float g2i = __fmul_rn(CPS, (float)(i - 64));
            float t2  = __fmul_rn(g2i, off1);
            f32x4 o;
#pragma unroll
            for (int q = 0; q < 4; ++q) {
                float arg = __fadd_rn(bx[q], t2);
                o[q] = __cosf(arg);   // v_cos_f32 path; err ~1e-5 << threshold
            }
            __builtin_nontemporal_store(o, &out4[baseg + g]);
        }
    }
}

extern "C" void kernel_launch(void* const* d_in, const int* in_sizes, int n_in,
                              void* d_out, int out_size, void* d_ws, size_t ws_size,
                              hipStream_t stream) {
    const float* rotvec = (const float*)d_in[0];
    const float* offs   = (const float*)d_in[1];
    const int*   index  = (const int*)d_in[2];
    float* out = (float*)d_out;
    int out_n4 = out_size / 4;   // float4 capacity of d_out

    pose_split_kernel<<<NBLK_ALL, 256, 0, stream>>>(rotvec, offs, index, out, out_n4);
}

// Round 9
// 44.562 us; speedup vs baseline: 1.2948x; 1.2948x over previous
//
#include <hip/hip_runtime.h>

#define NB 1024          // B
#define LSZ 128          // L
#define PTS_FLOATS (NB * 3 * LSZ * LSZ)     // 50,331,648
#define PTS4 (PTS_FLOATS / 4)               // 12,582,912 float4
#define TOT4 (PTS4 + NB * LSZ * LSZ / 4)    // 16,777,216 float4 = out_size/4 exactly
#define NBLK_PTS (NB * 3)                   // 3072 pts blocks (one per (b,i) slice)
#define NBLK_ALL (NBLK_PTS + NB)            // + 1024 phase blocks

typedef float f32x4 __attribute__((ext_vector_type(4)));

// Split grid, REGULAR stores (round-8 proved nontemporal stores regress 21%
// on this pure write stream — nt bypasses L2 write-combining on gfx950).
// pts inner loop is statement-for-statement the round-4/6 PASSING body:
// single-use mul chain -> fma contraction -> same last-ulp rounding at the
// mod-2pi wrap boundaries (round-5 proved hoisting a*x flips a wrap).
__global__ __launch_bounds__(256) void pose_split_kernel(
    const float* __restrict__ rotvec,
    const float* __restrict__ offs,
    const int* __restrict__ index,
    float* __restrict__ out,
    int out_n4) {
    const float PI_F   = (float)3.14159265358979323846;   // fl32(pi)
    const float TWO_PI = (float)6.28318530717958647692;   // fl32(2*pi)
    const float CPS    = (float)0.04908738521234052;      // fl32(2*pi/128)

    if (out_n4 < TOT4) return;   // defensive: harness sizing contract

    int t   = blockIdx.x;
    int tid = threadIdx.x;
    f32x4* out4 = reinterpret_cast<f32x4*>(out);

    if (t < NBLK_PTS) {
        int b = (int)((unsigned)t / 3u);
        int i = t - b * 3;
        int id = index[b];
        float rx = rotvec[id * 3 + 0];
        float ry = rotvec[id * 3 + 1];
        float rz = rotvec[id * 3 + 2];
        // theta = ||r||, sum order ((x^2+y^2)+z^2), all f32
        float theta = sqrtf(__fadd_rn(__fadd_rn(__fmul_rn(rx, rx), __fmul_rn(ry, ry)),
                                      __fmul_rn(rz, rz)));
        float denom = __fadd_rn(theta, 1e-6f);
        float kx = __fdiv_rn(rx, denom);
        float ky = __fdiv_rn(ry, denom);
        float kz = __fdiv_rn(rz, denom);
        float s  = sinf(theta);
        float c1 = __fsub_rn(1.0f, cosf(theta));
        float kx2 = __fmul_rn(kx, kx), ky2 = __fmul_rn(ky, ky), kz2 = __fmul_rn(kz, kz);
        float kxky = __fmul_rn(kx, ky), kxkz = __fmul_rn(kx, kz), kykz = __fmul_rn(ky, kz);
        float K2_00 = __fadd_rn(-kz2, -ky2);
        float K2_10 = kxky;
        float K2_20 = kxkz;
        float K2_01 = kxky;
        float K2_11 = __fadd_rn(-kz2, -kx2);
        float K2_21 = kykz;
        float R00 = __fadd_rn(1.0f, __fmul_rn(c1, K2_00));
        float R10 = __fadd_rn(__fmul_rn(s, kz),  __fmul_rn(c1, K2_10));
        float R20 = __fadd_rn(__fmul_rn(s, -ky), __fmul_rn(c1, K2_20));
        float R01 = __fadd_rn(__fmul_rn(s, -kz), __fmul_rn(c1, K2_01));
        float R11 = __fadd_rn(1.0f, __fmul_rn(c1, K2_11));
        float R21 = __fadd_rn(__fmul_rn(s, kx),  __fmul_rn(c1, K2_21));
        // Row reversal: slice i uses R row (2-i), cols 0 (x) and 1 (y)
        float a = (i == 0) ? R20 : (i == 1) ? R10 : R00;
        float c = (i == 0) ? R21 : (i == 1) ? R11 : R01;

        int base4 = t * 4096;    // == (b*3+i)*4096
        // EXACT round-4/6 inner loop body (statement-for-statement).
        for (int k4 = tid; k4 < 4096; k4 += 256) {
            int k0  = k4 << 2;
            int row = k0 >> 7;                       // 4 consecutive never cross a row
            float y  = __fmul_rn(PI_F, (float)(row - 64) * 0.015625f);
            float cy = __fmul_rn(c, y);
            f32x4 o;
#pragma unroll
            for (int q = 0; q < 4; ++q) {
                int col = ((k0 + q) & 127) - 64;
                float x = __fmul_rn(PI_F, (float)col * 0.015625f);
                float v = __fadd_rn(__fmul_rn(a, x), cy);  // single-use mul chain
                float w = __fadd_rn(v, PI_F);
                // exact mod(w, 2pi) for w in (-2pi, 2*2pi)
                float r = (w >= TWO_PI) ? __fsub_rn(w, TWO_PI) : w;
                r = (r < 0.0f) ? __fadd_rn(r, TWO_PI) : r;
                o[q] = __fsub_rn(r, PI_F);
            }
            out4[base4 + k4] = o;
        }
    } else {
        int b  = t - NBLK_PTS;
        int id = index[b];
        float off0 = -offs[id * 2 + 0];
        float off1 = -offs[id * 2 + 1];

        // Hoist is SAFE here: cos is continuous, ~1e-5 rad arg perturbation
        // cannot cross any cliff (threshold 0.0628).
        int j0 = (tid & 31) << 2;
        float bx[4];
#pragma unroll
        for (int q = 0; q < 4; ++q) {
            float g2j = __fmul_rn(CPS, (float)(j0 + q - 64));
            bx[q] = __fmul_rn(g2j, off0);
        }

        int baseg = PTS4 + b * 4096;
        for (int g = tid; g < 4096; g += 256) {
            int i = g >> 5;            // row 0..127
            float g2i = __fmul_rn(CPS, (float)(i - 64));
            float t2  = __fmul_rn(g2i, off1);
            f32x4 o;
#pragma unroll
            for (int q = 0; q < 4; ++q) {
                float arg = __fadd_rn(bx[q], t2);
                o[q] = __cosf(arg);   // v_cos_f32 path; err ~1e-5 << threshold
            }
            out4[baseg + g] = o;
        }
    }
}

extern "C" void kernel_launch(void* const* d_in, const int* in_sizes, int n_in,
                              void* d_out, int out_size, void* d_ws, size_t ws_size,
                              hipStream_t stream) {
    const float* rotvec = (const float*)d_in[0];
    const float* offs   = (const float*)d_in[1];
    const int*   index  = (const int*)d_in[2];
    float* out = (float*)d_out;
    int out_n4 = out_size / 4;   // float4 capacity of d_out

    pose_split_kernel<<<NBLK_ALL, 256, 0, stream>>>(rotvec, offs, index, out, out_n4);
}